// Round 3
// baseline (367.188 us; speedup 1.0000x reference)
//
#include <hip/hip_runtime.h>

// MultiScaleDeformableAttention forward (Deformable-DETR), fp32.
// B=4, S=21760, H=8, D=32, Q=10000, L=4, P=4.
// Levels (static): (128,128),(64,64),(32,32),(16,16); starts 0,16384,20480,21504.
//
// Round 3: dedupe per-group scalar math. Group = 4 lanes per (b,q,h); each
// lane owns TWO float4 chunks of D (chunk c and c+4, i.e. bytes c*16 and
// c*16+64 of the 128B value line). Address/weight math redundancy drops
// 8x -> 4x; wave count halves. 32-bit voffset addressing from a wave-uniform
// slice base; 2nd chunk via the load's offset:64 immediate.
// Keeps round-2 XCD-affine swizzle (blockIdx%8 = head; value slice 2.78 MB
// fits one XCD L2 -> FETCH_SIZE ~103 MB).

#define MSDA_B 4
#define MSDA_Q 10000
#define MSDA_H 8
#define MSDA_D 32
#define MSDA_L 4
#define MSDA_P 4
#define MSDA_S 21760

// 64 q per block (256 threads / 4 lanes per q); blocks per (b,h) slice
#define MSDA_QBLK 157   // ceil(10000/64)

__global__ __launch_bounds__(256) void msda_fwd_kernel(
    const float* __restrict__ value,   // [B,S,H,D]
    const float* __restrict__ loc,     // [B,Q,H,L,P,2]
    const float* __restrict__ aw,      // [B,Q,H,L,P]
    float* __restrict__ out)           // [B,Q,H,D]
{
    constexpr int H = MSDA_H, D = MSDA_D, L = MSDA_L, P = MSDA_P;
    constexpr int S = MSDA_S, Q = MSDA_Q;
    // static level metadata (log2 sizes: levels are square powers of two)
    const int lvl_sh[4]    = {7, 6, 5, 4};
    const int lvl_start[4] = {0, 16384, 20480, 21504};

    // ---- XCD-affine decode: blockIdx%8 = XCD = head ----
    int i = blockIdx.x;
    int h = i & 7;
    int r = i >> 3;
    int b = r / MSDA_QBLK;
    int qb = r - b * MSDA_QBLK;

    int q = qb * 64 + (threadIdx.x >> 2);
    if (q >= Q) return;
    const unsigned coff = (threadIdx.x & 3) * 16;   // byte offset of chunk c

    const size_t bqh = ((size_t)b * Q + q) * H + h;
    const float4* lp4 = (const float4*)(loc + bqh * (L * P * 2));
    const float4* wp4 = (const float4*)(aw  + bqh * (L * P));
    // wave-uniform slice base for (b, h): value + b*S*H*D + h*D
    const char* vb = (const char*)(value + (size_t)b * S * H * D + h * D);

    float4 acc0 = {0.f, 0.f, 0.f, 0.f};
    float4 acc1 = {0.f, 0.f, 0.f, 0.f};

#pragma unroll
    for (int l = 0; l < L; ++l) {
        const int sh = lvl_sh[l];
        const int hw = 1 << sh;
        const float fhw = (float)hw;
        const int start = lvl_start[l];

        // per-level loc (8 floats x2) + weights (4 floats)
        float4 la = lp4[2 * l + 0];
        float4 lb = lp4[2 * l + 1];
        float4 wv = wp4[l];
        float lx[4] = {la.x, la.z, lb.x, lb.z};
        float ly[4] = {la.y, la.w, lb.y, lb.w};
        float wl[4] = {wv.x, wv.y, wv.z, wv.w};

#pragma unroll
        for (int p = 0; p < P; ++p) {
            float x = lx[p] * fhw - 0.5f;
            float y = ly[p] * fhw - 0.5f;
            float xf = floorf(x), yf = floorf(y);
            float fx = x - xf, fy = y - yf;
            int x0 = (int)xf, y0 = (int)yf;
            int x1 = x0 + 1, y1 = y0 + 1;

            float vx0 = ((unsigned)x0 < (unsigned)hw) ? 1.f : 0.f;
            float vx1 = ((unsigned)x1 < (unsigned)hw) ? 1.f : 0.f;
            float vy0 = ((unsigned)y0 < (unsigned)hw) ? 1.f : 0.f;
            float vy1 = ((unsigned)y1 < (unsigned)hw) ? 1.f : 0.f;

            int cx0 = min(max(x0, 0), hw - 1);
            int cx1 = min(max(x1, 0), hw - 1);
            int cy0 = min(max(y0, 0), hw - 1);
            int cy1 = min(max(y1, 0), hw - 1);

            float wgt = wl[p];
            float w00 = (1.f - fx) * (1.f - fy) * wgt * vx0 * vy0;
            float w01 = fx * (1.f - fy) * wgt * vx1 * vy0;
            float w10 = (1.f - fx) * fy * wgt * vx0 * vy1;
            float w11 = fx * fy * wgt * vx1 * vy1;

            // 32-bit byte offsets: s*H*D*4 = s<<10, plus lane chunk offset
            int r0 = start + (cy0 << sh);
            int r1 = start + (cy1 << sh);
            unsigned o00 = ((unsigned)(r0 + cx0) << 10) + coff;
            unsigned o01 = ((unsigned)(r0 + cx1) << 10) + coff;
            unsigned o10 = ((unsigned)(r1 + cx0) << 10) + coff;
            unsigned o11 = ((unsigned)(r1 + cx1) << 10) + coff;

            float4 a00 = *(const float4*)(vb + o00);
            float4 b00 = *(const float4*)(vb + o00 + 64);
            float4 a01 = *(const float4*)(vb + o01);
            float4 b01 = *(const float4*)(vb + o01 + 64);
            float4 a10 = *(const float4*)(vb + o10);
            float4 b10 = *(const float4*)(vb + o10 + 64);
            float4 a11 = *(const float4*)(vb + o11);
            float4 b11 = *(const float4*)(vb + o11 + 64);

            acc0.x += w00 * a00.x + w01 * a01.x + w10 * a10.x + w11 * a11.x;
            acc0.y += w00 * a00.y + w01 * a01.y + w10 * a10.y + w11 * a11.y;
            acc0.z += w00 * a00.z + w01 * a01.z + w10 * a10.z + w11 * a11.z;
            acc0.w += w00 * a00.w + w01 * a01.w + w10 * a10.w + w11 * a11.w;
            acc1.x += w00 * b00.x + w01 * b01.x + w10 * b10.x + w11 * b11.x;
            acc1.y += w00 * b00.y + w01 * b01.y + w10 * b10.y + w11 * b11.y;
            acc1.z += w00 * b00.z + w01 * b01.z + w10 * b10.z + w11 * b11.z;
            acc1.w += w00 * b00.w + w01 * b01.w + w10 * b10.w + w11 * b11.w;
        }
    }

    // out[b,q,h,:]: chunk c and c+4
    float4* op = (float4*)out + bqh * (D / 4) + (threadIdx.x & 3);
    op[0] = acc0;
    op[4] = acc1;
}

extern "C" void kernel_launch(void* const* d_in, const int* in_sizes, int n_in,
                              void* d_out, int out_size, void* d_ws, size_t ws_size,
                              hipStream_t stream) {
    const float* value = (const float*)d_in[0];
    const float* loc = (const float*)d_in[3];
    const float* aw  = (const float*)d_in[4];
    float* out = (float*)d_out;

    // 8 XCDs x B slices x 157 q-blocks = 5024 blocks
    const int grid = 8 * MSDA_B * MSDA_QBLK;
    msda_fwd_kernel<<<grid, 256, 0, stream>>>(value, loc, aw, out);
}

// Round 4
// 342.180 us; speedup vs baseline: 1.0731x; 1.0731x over previous
//
#include <hip/hip_runtime.h>

// MultiScaleDeformableAttention forward (Deformable-DETR), fp32.
// B=4, S=21760, H=8, D=32, Q=10000, L=4, P=4.
// Levels (static): (128,128),(64,64),(32,32),(16,16); starts 0,16384,20480,21504.
//
// Round 4: latency-hiding via per-wave MLP. Round-3 showed the kernel is
// gather-latency bound (VALU dedup halved VALUBusy, time regressed with wave
// count). Structure: back to 8 lanes per (b,q,h) group (round-1 layout,
// 1 cacheline per corner per group), but per LEVEL we compute all 16 corner
// offsets (4 points x 4 corners), issue all 16 float4 loads back-to-back,
// then compute weights, then accumulate in issue order -> compiler emits
// partial vmcnt waits; ~16 outstanding loads per wave vs ~4 before.
// Keeps XCD-affine swizzle (blockIdx%8 = head, per-(b,h) 2.78MB slice stays
// L2-resident) and 32-bit voffset addressing from a wave-uniform base.

#define MSDA_B 4
#define MSDA_Q 10000
#define MSDA_H 8
#define MSDA_D 32
#define MSDA_L 4
#define MSDA_P 4
#define MSDA_S 21760

#define MSDA_QBLK 313   // ceil(10000/32) q-blocks per (b,h) slice

__global__ __launch_bounds__(256, 4) void msda_fwd_kernel(
    const float* __restrict__ value,   // [B,S,H,D]
    const float* __restrict__ loc,     // [B,Q,H,L,P,2]
    const float* __restrict__ aw,      // [B,Q,H,L,P]
    float* __restrict__ out)           // [B,Q,H,D]
{
    constexpr int H = MSDA_H, D = MSDA_D, L = MSDA_L, P = MSDA_P;
    constexpr int S = MSDA_S, Q = MSDA_Q;
    const int lvl_sh[4]    = {7, 6, 5, 4};
    const int lvl_start[4] = {0, 16384, 20480, 21504};

    // ---- XCD-affine decode: blockIdx%8 = XCD = head ----
    int i = blockIdx.x;
    int h = i & 7;
    int r = i >> 3;
    int b = r / MSDA_QBLK;
    int qb = r - b * MSDA_QBLK;

    int q = qb * 32 + (threadIdx.x >> 3);
    if (q >= Q) return;
    const unsigned coff = (threadIdx.x & 7) * 16;   // byte offset of my float4 chunk

    const size_t bqh = ((size_t)b * Q + q) * H + h;
    const float4* lp4 = (const float4*)(loc + bqh * (L * P * 2));
    const float4* wp4 = (const float4*)(aw  + bqh * (L * P));
    // wave-uniform slice base for (b,h)
    const char* vb = (const char*)(value + ((size_t)b * S * H + h) * D);

    float4 acc = {0.f, 0.f, 0.f, 0.f};

#pragma unroll
    for (int l = 0; l < L; ++l) {
        const int sh = lvl_sh[l];
        const int hw = 1 << sh;
        const float fhw = (float)hw;
        const int start = lvl_start[l];

        float4 la = lp4[2 * l + 0];
        float4 lb = lp4[2 * l + 1];
        float4 wv = wp4[l];
        float lx[4] = {la.x, la.z, lb.x, lb.z};
        float ly[4] = {la.y, la.w, lb.y, lb.w};
        float wl[4] = {wv.x, wv.y, wv.z, wv.w};

        unsigned off[P][4];
        float fxs[P], fys[P];
        float vxy[P][4];   // per-corner validity

        // ---- phase 1: all addresses ----
#pragma unroll
        for (int p = 0; p < P; ++p) {
            float x = lx[p] * fhw - 0.5f;
            float y = ly[p] * fhw - 0.5f;
            float xf = floorf(x), yf = floorf(y);
            fxs[p] = x - xf;
            fys[p] = y - yf;
            int x0 = (int)xf, y0 = (int)yf;
            int x1 = x0 + 1, y1 = y0 + 1;

            float vx0 = ((unsigned)x0 < (unsigned)hw) ? 1.f : 0.f;
            float vx1 = ((unsigned)x1 < (unsigned)hw) ? 1.f : 0.f;
            float vy0 = ((unsigned)y0 < (unsigned)hw) ? 1.f : 0.f;
            float vy1 = ((unsigned)y1 < (unsigned)hw) ? 1.f : 0.f;
            vxy[p][0] = vx0 * vy0;
            vxy[p][1] = vx1 * vy0;
            vxy[p][2] = vx0 * vy1;
            vxy[p][3] = vx1 * vy1;

            int cx0 = min(max(x0, 0), hw - 1);
            int cx1 = min(max(x1, 0), hw - 1);
            int cy0 = min(max(y0, 0), hw - 1);
            int cy1 = min(max(y1, 0), hw - 1);

            int r0 = start + (cy0 << sh);
            int r1 = start + (cy1 << sh);
            off[p][0] = ((unsigned)(r0 + cx0) << 10) + coff;
            off[p][1] = ((unsigned)(r0 + cx1) << 10) + coff;
            off[p][2] = ((unsigned)(r1 + cx0) << 10) + coff;
            off[p][3] = ((unsigned)(r1 + cx1) << 10) + coff;
        }

        // ---- phase 2: issue all 16 loads back-to-back ----
        float4 v[P][4];
#pragma unroll
        for (int p = 0; p < P; ++p) {
#pragma unroll
            for (int c = 0; c < 4; ++c) {
                v[p][c] = *(const float4*)(vb + off[p][c]);
            }
        }

        // ---- phase 3: weights (VALU overlaps load latency) ----
        float w[P][4];
#pragma unroll
        for (int p = 0; p < P; ++p) {
            float fx = fxs[p], fy = fys[p];
            float wgt = wl[p];
            w[p][0] = (1.f - fx) * (1.f - fy) * wgt * vxy[p][0];
            w[p][1] = fx * (1.f - fy) * wgt * vxy[p][1];
            w[p][2] = (1.f - fx) * fy * wgt * vxy[p][2];
            w[p][3] = fx * fy * wgt * vxy[p][3];
        }

        // ---- phase 4: accumulate in issue order (partial vmcnt waits) ----
#pragma unroll
        for (int p = 0; p < P; ++p) {
#pragma unroll
            for (int c = 0; c < 4; ++c) {
                acc.x += w[p][c] * v[p][c].x;
                acc.y += w[p][c] * v[p][c].y;
                acc.z += w[p][c] * v[p][c].z;
                acc.w += w[p][c] * v[p][c].w;
            }
        }
    }

    ((float4*)out)[bqh * (D / 4) + (threadIdx.x & 7)] = acc;
}

extern "C" void kernel_launch(void* const* d_in, const int* in_sizes, int n_in,
                              void* d_out, int out_size, void* d_ws, size_t ws_size,
                              hipStream_t stream) {
    const float* value = (const float*)d_in[0];
    const float* loc = (const float*)d_in[3];
    const float* aw  = (const float*)d_in[4];
    float* out = (float*)d_out;

    // 8 XCDs x B slices x 313 q-blocks = 10016 blocks
    const int grid = 8 * MSDA_B * MSDA_QBLK;
    msda_fwd_kernel<<<grid, 256, 0, stream>>>(value, loc, aw, out);
}

// Round 5
// 282.898 us; speedup vs baseline: 1.2979x; 1.2096x over previous
//
#include <hip/hip_runtime.h>
#include <hip/hip_fp16.h>

// MultiScaleDeformableAttention forward (Deformable-DETR), fp32 in/out.
// B=4, S=21760, H=8, D=32, Q=10000, L=4, P=4.
// Levels (static): (128,128),(64,64),(32,32),(16,16); starts 0,16384,20480,21504.
//
// Round 5: the kernel is pinned at ~206-212us regardless of occupancy (25-60%)
// and VALU (15-35%) -> per-CU random-gather request wall (L1 MSHR x L2 latency,
// ~12 TB/s effective on 128B line requests). Attack bytes+requests:
//   pre-pass: value fp32 [B,S,H,D] -> fp16 [B,H,S,D] in d_ws (streaming).
//   gathers: 64B per corner (half bytes); x-adjacent corners share a 128B
//   line 50% of the time -> MSHR merge cuts unique line requests ~25%.
// fp32 accumulate; fp16 quantization ~5e-4 << 2.2e-2 threshold.
// Keeps XCD-affine swizzle (blockIdx%8 = head; per-(b,h) slice now 1.39 MB).

#define MSDA_B 4
#define MSDA_Q 10000
#define MSDA_H 8
#define MSDA_D 32
#define MSDA_L 4
#define MSDA_P 4
#define MSDA_S 21760

#define MSDA_QBLK16 157   // ceil(10000/64) q-blocks per (b,h) slice (fp16 path)
#define MSDA_QBLK32 313   // ceil(10000/32) (fp32 fallback path)

// ---------------- pre-pass: fp32 [B,S,H,D] -> fp16 [B,H,S,D] ----------------
__global__ __launch_bounds__(256) void msda_convert_kernel(
    const float* __restrict__ value, __half* __restrict__ vw)
{
    int o4 = blockIdx.x * 256 + threadIdx.x;      // index of 4 halves in output
    int d4 = o4 & 7;                               // D/4 = 8
    int rest = o4 >> 3;                            // (b*H + h)*S + s
    int s = rest % MSDA_S;
    int bh = rest / MSDA_S;
    int b = bh >> 3, h = bh & 7;
    float4 v = *(const float4*)(value +
        (((size_t)b * MSDA_S + s) * MSDA_H + h) * MSDA_D + 4 * d4);
    union { __half2 h2[2]; uint2 u; } pk;
    pk.h2[0] = __floats2half2_rn(v.x, v.y);
    pk.h2[1] = __floats2half2_rn(v.z, v.w);
    ((uint2*)vw)[o4] = pk.u;
}

// ---------------- main kernel (fp16 gather path) ----------------
__global__ __launch_bounds__(256) void msda_fwd_fp16_kernel(
    const __half* __restrict__ vw,     // [B,H,S,D] fp16
    const float* __restrict__ loc,     // [B,Q,H,L,P,2]
    const float* __restrict__ aw,      // [B,Q,H,L,P]
    float* __restrict__ out)           // [B,Q,H,D]
{
    constexpr int H = MSDA_H, D = MSDA_D, L = MSDA_L, P = MSDA_P;
    constexpr int S = MSDA_S, Q = MSDA_Q;
    const int lvl_sh[4]    = {7, 6, 5, 4};
    const int lvl_start[4] = {0, 16384, 20480, 21504};

    // XCD-affine: blockIdx%8 = XCD = head
    int i = blockIdx.x;
    int h = i & 7;
    int r = i >> 3;
    int b = r / MSDA_QBLK16;
    int qb = r - b * MSDA_QBLK16;

    int q = qb * 64 + (threadIdx.x >> 2);         // 4 lanes per (b,q,h)
    if (q >= Q) return;
    const int lane = threadIdx.x & 3;
    const unsigned coff = (unsigned)lane * 16;    // 16B = 8 halves = d[8k..8k+7]

    const size_t bqh = ((size_t)b * Q + q) * H + h;
    const float4* lp4 = (const float4*)(loc + bqh * (L * P * 2));
    const float4* wp4 = (const float4*)(aw  + bqh * (L * P));
    // wave-uniform fp16 slice base for (b,h): pixel stride = D*2 = 64 B
    const char* vb = (const char*)(vw + (size_t)(b * H + h) * S * D);

    float2 acc[4] = {{0.f,0.f},{0.f,0.f},{0.f,0.f},{0.f,0.f}};

#pragma unroll
    for (int l = 0; l < L; ++l) {
        const int sh = lvl_sh[l];
        const int hw = 1 << sh;
        const float fhw = (float)hw;
        const int start = lvl_start[l];

        float4 la = lp4[2 * l + 0];
        float4 lb = lp4[2 * l + 1];
        float4 wv = wp4[l];
        float lx[4] = {la.x, la.z, lb.x, lb.z};
        float ly[4] = {la.y, la.w, lb.y, lb.w};
        float wl[4] = {wv.x, wv.y, wv.z, wv.w};

#pragma unroll
        for (int p = 0; p < P; ++p) {
            float x = lx[p] * fhw - 0.5f;
            float y = ly[p] * fhw - 0.5f;
            float xf = floorf(x), yf = floorf(y);
            float fx = x - xf, fy = y - yf;
            int x0 = (int)xf, y0 = (int)yf;
            int x1 = x0 + 1, y1 = y0 + 1;

            float vx0 = ((unsigned)x0 < (unsigned)hw) ? 1.f : 0.f;
            float vx1 = ((unsigned)x1 < (unsigned)hw) ? 1.f : 0.f;
            float vy0 = ((unsigned)y0 < (unsigned)hw) ? 1.f : 0.f;
            float vy1 = ((unsigned)y1 < (unsigned)hw) ? 1.f : 0.f;

            int cx0 = min(max(x0, 0), hw - 1);
            int cx1 = min(max(x1, 0), hw - 1);
            int cy0 = min(max(y0, 0), hw - 1);
            int cy1 = min(max(y1, 0), hw - 1);

            // pixel byte offset = pixel_index << 6 (64 B per pixel)
            int r0 = start + (cy0 << sh);
            int r1 = start + (cy1 << sh);
            unsigned o00 = ((unsigned)(r0 + cx0) << 6) + coff;
            unsigned o01 = ((unsigned)(r0 + cx1) << 6) + coff;
            unsigned o10 = ((unsigned)(r1 + cx0) << 6) + coff;
            unsigned o11 = ((unsigned)(r1 + cx1) << 6) + coff;

            // issue the 4 corner loads (x-pairs share a 128B line 50% of time)
            union U { uint4 u; __half2 h2[4]; };
            U u00, u01, u10, u11;
            u00.u = *(const uint4*)(vb + o00);
            u01.u = *(const uint4*)(vb + o01);
            u10.u = *(const uint4*)(vb + o10);
            u11.u = *(const uint4*)(vb + o11);

            float wgt = wl[p];
            float w00 = (1.f - fx) * (1.f - fy) * wgt * vx0 * vy0;
            float w01 = fx * (1.f - fy) * wgt * vx1 * vy0;
            float w10 = (1.f - fx) * fy * wgt * vx0 * vy1;
            float w11 = fx * fy * wgt * vx1 * vy1;

#pragma unroll
            for (int j = 0; j < 4; ++j) {
                float2 f00 = __half22float2(u00.h2[j]);
                float2 f01 = __half22float2(u01.h2[j]);
                float2 f10 = __half22float2(u10.h2[j]);
                float2 f11 = __half22float2(u11.h2[j]);
                acc[j].x += w00 * f00.x + w01 * f01.x + w10 * f10.x + w11 * f11.x;
                acc[j].y += w00 * f00.y + w01 * f01.y + w10 * f10.y + w11 * f11.y;
            }
        }
    }

    // lane owns d[8*lane .. 8*lane+7] -> float4 chunks 2*lane, 2*lane+1
    float4* op = (float4*)out + bqh * (D / 4) + lane * 2;
    op[0] = make_float4(acc[0].x, acc[0].y, acc[1].x, acc[1].y);
    op[1] = make_float4(acc[2].x, acc[2].y, acc[3].x, acc[3].y);
}

// ---------------- fp32 fallback (round-4 kernel) ----------------
__global__ __launch_bounds__(256, 4) void msda_fwd_fp32_kernel(
    const float* __restrict__ value, const float* __restrict__ loc,
    const float* __restrict__ aw, float* __restrict__ out)
{
    constexpr int H = MSDA_H, D = MSDA_D, L = MSDA_L, P = MSDA_P;
    constexpr int S = MSDA_S, Q = MSDA_Q;
    const int lvl_sh[4]    = {7, 6, 5, 4};
    const int lvl_start[4] = {0, 16384, 20480, 21504};

    int i = blockIdx.x;
    int h = i & 7;
    int r = i >> 3;
    int b = r / MSDA_QBLK32;
    int qb = r - b * MSDA_QBLK32;

    int q = qb * 32 + (threadIdx.x >> 3);
    if (q >= Q) return;
    const unsigned coff = (threadIdx.x & 7) * 16;

    const size_t bqh = ((size_t)b * Q + q) * H + h;
    const float4* lp4 = (const float4*)(loc + bqh * (L * P * 2));
    const float4* wp4 = (const float4*)(aw  + bqh * (L * P));
    const char* vb = (const char*)(value + ((size_t)b * S * H + h) * D);

    float4 acc = {0.f, 0.f, 0.f, 0.f};

#pragma unroll
    for (int l = 0; l < L; ++l) {
        const int sh = lvl_sh[l];
        const int hw = 1 << sh;
        const float fhw = (float)hw;
        const int start = lvl_start[l];

        float4 la = lp4[2 * l + 0];
        float4 lb = lp4[2 * l + 1];
        float4 wv = wp4[l];
        float lx[4] = {la.x, la.z, lb.x, lb.z};
        float ly[4] = {la.y, la.w, lb.y, lb.w};
        float wl[4] = {wv.x, wv.y, wv.z, wv.w};

#pragma unroll
        for (int p = 0; p < P; ++p) {
            float x = lx[p] * fhw - 0.5f;
            float y = ly[p] * fhw - 0.5f;
            float xf = floorf(x), yf = floorf(y);
            float fx = x - xf, fy = y - yf;
            int x0 = (int)xf, y0 = (int)yf;
            int x1 = x0 + 1, y1 = y0 + 1;

            float vx0 = ((unsigned)x0 < (unsigned)hw) ? 1.f : 0.f;
            float vx1 = ((unsigned)x1 < (unsigned)hw) ? 1.f : 0.f;
            float vy0 = ((unsigned)y0 < (unsigned)hw) ? 1.f : 0.f;
            float vy1 = ((unsigned)y1 < (unsigned)hw) ? 1.f : 0.f;

            int cx0 = min(max(x0, 0), hw - 1);
            int cx1 = min(max(x1, 0), hw - 1);
            int cy0 = min(max(y0, 0), hw - 1);
            int cy1 = min(max(y1, 0), hw - 1);

            float wgt = wl[p];
            float w00 = (1.f - fx) * (1.f - fy) * wgt * vx0 * vy0;
            float w01 = fx * (1.f - fy) * wgt * vx1 * vy0;
            float w10 = (1.f - fx) * fy * wgt * vx0 * vy1;
            float w11 = fx * fy * wgt * vx1 * vy1;

            int r0 = start + (cy0 << sh);
            int r1 = start + (cy1 << sh);
            unsigned o00 = ((unsigned)(r0 + cx0) << 10) + coff;
            unsigned o01 = ((unsigned)(r0 + cx1) << 10) + coff;
            unsigned o10 = ((unsigned)(r1 + cx0) << 10) + coff;
            unsigned o11 = ((unsigned)(r1 + cx1) << 10) + coff;

            float4 v00 = *(const float4*)(vb + o00);
            float4 v01 = *(const float4*)(vb + o01);
            float4 v10 = *(const float4*)(vb + o10);
            float4 v11 = *(const float4*)(vb + o11);

            acc.x += w00 * v00.x + w01 * v01.x + w10 * v10.x + w11 * v11.x;
            acc.y += w00 * v00.y + w01 * v01.y + w10 * v10.y + w11 * v11.y;
            acc.z += w00 * v00.z + w01 * v01.z + w10 * v10.z + w11 * v11.z;
            acc.w += w00 * v00.w + w01 * v01.w + w10 * v10.w + w11 * v11.w;
        }
    }

    ((float4*)out)[bqh * (D / 4) + (threadIdx.x & 7)] = acc;
}

extern "C" void kernel_launch(void* const* d_in, const int* in_sizes, int n_in,
                              void* d_out, int out_size, void* d_ws, size_t ws_size,
                              hipStream_t stream) {
    const float* value = (const float*)d_in[0];
    const float* loc = (const float*)d_in[3];
    const float* aw  = (const float*)d_in[4];
    float* out = (float*)d_out;

    const size_t need = (size_t)MSDA_B * MSDA_H * MSDA_S * MSDA_D * sizeof(__half);
    if (ws_size >= need) {
        __half* vw = (__half*)d_ws;
        // 22,282,240 halves / 4 per thread / 256 per block = 21,760 blocks
        msda_convert_kernel<<<(MSDA_B * MSDA_S * MSDA_H * MSDA_D / 4 + 255) / 256,
                              256, 0, stream>>>(value, vw);
        const int grid = 8 * MSDA_B * MSDA_QBLK16;   // 5024
        msda_fwd_fp16_kernel<<<grid, 256, 0, stream>>>(vw, loc, aw, out);
    } else {
        const int grid = 8 * MSDA_B * MSDA_QBLK32;   // 10016
        msda_fwd_fp32_kernel<<<grid, 256, 0, stream>>>(value, loc, aw, out);
    }
}